// Round 7
// baseline (444.440 us; speedup 1.0000x reference)
//
#include <hip/hip_runtime.h>

typedef unsigned short u16;
typedef __bf16 bf16x8 __attribute__((ext_vector_type(8)));
typedef short s16x4 __attribute__((ext_vector_type(4)));
typedef float f32x4 __attribute__((ext_vector_type(4)));

union U4B8 { uint4 u; bf16x8 v; u16 s[8]; };
union U2S4 { uint2 u2; s16x4 s; };

__device__ __forceinline__ u16 f2b(float f) {
  union { float f; unsigned u; } x; x.f = f;
  unsigned u = x.u + 0x7fffu + ((x.u >> 16) & 1u);
  return (u16)(u >> 16);
}

// 2x bf16 pack. s_nop 3 embedded: the result feeds MFMA SrcA directly; the
// VALU-write->MFMA-read hazard wait-states can't be inserted by the compiler
// for an inline-asm producer (round-3/round-6 lesson), so we carry them here.
__device__ __forceinline__ unsigned cvtpk(float lo, float hi) {
  unsigned r;
  asm("v_cvt_pk_bf16_f32 %0, %1, %2\n\ts_nop 3" : "=v"(r) : "v"(lo), "v"(hi));
  return r;
}

// ---------------- fp32 -> bf16 elementwise (for x) ----------------
__global__ __launch_bounds__(256) void cvt_f32_bf16(const float* __restrict__ in,
                                                    u16* __restrict__ out) {
  int i = blockIdx.x * 256 + threadIdx.x;
  float4 v = ((const float4*)in)[i];
  ushort4 h;
  h.x = f2b(v.x); h.y = f2b(v.y); h.z = f2b(v.z); h.w = f2b(v.w);
  ((ushort4*)out)[i] = h;
}

// ---------------- W [K][N] fp32 -> Wt [N][K] bf16 ----------------
__global__ __launch_bounds__(256) void transpose_w(const float* __restrict__ in,
                                                   u16* __restrict__ out, int K, int N) {
  __shared__ u16 t[64 * 72];
  int k0 = blockIdx.y * 64, n0 = blockIdx.x * 64;
  int tid = threadIdx.x;
#pragma unroll
  for (int p = 0; p < 4; ++p) {
    int idx = p * 256 + tid;
    int k = idx >> 4, ng = idx & 15;
    float4 v = *(const float4*)(in + (k0 + k) * N + n0 + ng * 4);
    t[(ng * 4 + 0) * 72 + k] = f2b(v.x);
    t[(ng * 4 + 1) * 72 + k] = f2b(v.y);
    t[(ng * 4 + 2) * 72 + k] = f2b(v.z);
    t[(ng * 4 + 3) * 72 + k] = f2b(v.w);
  }
  __syncthreads();
#pragma unroll
  for (int p = 0; p < 2; ++p) {
    int idx = p * 256 + tid;
    int n = idx >> 3, kg = (idx & 7) * 8;
    uint4 u = *(uint4*)(&t[n * 72 + kg]);
    *(uint4*)(out + (n0 + n) * K + k0 + kg) = u;
  }
}

// ---------------- GEMM: C[M][N] = A[M][1024] @ Wt^T + bias ----------------
// MODE 0: N=3072, out -> Q/K/V bf16 [64][2048][64], q scaled by 0.125*log2(e)
// MODE 1: N=1024, out -> fp32 d_out
template <int MODE>
__global__ __launch_bounds__(256) void gemm_bf16(const u16* __restrict__ A,
                                                 const u16* __restrict__ B,
                                                 const float* __restrict__ bias,
                                                 float* __restrict__ outf,
                                                 u16* __restrict__ Qo, u16* __restrict__ Ko,
                                                 u16* __restrict__ Vo) {
  __shared__ u16 a_lds[128 * 32];
  __shared__ u16 b_lds[128 * 32];
  int tid = threadIdx.x;
  int l = tid & 63, w = tid >> 6;
  int wr = (w >> 1) * 64, wc = (w & 1) * 64;
  int m0 = blockIdx.y * 128, n0 = blockIdx.x * 128;
  int r15 = l & 15;
  int ka = (l >> 4) * 8;
  int r0 = tid >> 2, kg0 = (tid & 3) * 8;
  f32x4 acc[4][4] = {};
  for (int kt = 0; kt < 32; ++kt) {
    int k0 = kt * 32;
    __syncthreads();
    __builtin_amdgcn_global_load_lds(
        (const __attribute__((address_space(1))) void*)(A + (m0 + r0) * 1024 + k0 + kg0),
        (__attribute__((address_space(3))) void*)(&a_lds[tid * 8]), 16, 0, 0);
    __builtin_amdgcn_global_load_lds(
        (const __attribute__((address_space(1))) void*)(A + (m0 + 64 + r0) * 1024 + k0 + kg0),
        (__attribute__((address_space(3))) void*)(&a_lds[2048 + tid * 8]), 16, 0, 0);
    __builtin_amdgcn_global_load_lds(
        (const __attribute__((address_space(1))) void*)(B + (n0 + r0) * 1024 + k0 + kg0),
        (__attribute__((address_space(3))) void*)(&b_lds[tid * 8]), 16, 0, 0);
    __builtin_amdgcn_global_load_lds(
        (const __attribute__((address_space(1))) void*)(B + (n0 + 64 + r0) * 1024 + k0 + kg0),
        (__attribute__((address_space(3))) void*)(&b_lds[2048 + tid * 8]), 16, 0, 0);
    __syncthreads();
    bf16x8 af[4], bf[4];
#pragma unroll
    for (int i = 0; i < 4; ++i) {
      U4B8 ua; ua.u = *(uint4*)(&a_lds[(wr + i * 16 + r15) * 32 + ka]); af[i] = ua.v;
      U4B8 ub; ub.u = *(uint4*)(&b_lds[(wc + i * 16 + r15) * 32 + ka]); bf[i] = ub.v;
    }
#pragma unroll
    for (int i = 0; i < 4; ++i)
#pragma unroll
      for (int j = 0; j < 4; ++j)
        acc[i][j] = __builtin_amdgcn_mfma_f32_16x16x32_bf16(af[i], bf[j], acc[i][j], 0, 0, 0);
  }
  int rbase = (l >> 4) * 4;
#pragma unroll
  for (int i = 0; i < 4; ++i)
#pragma unroll
    for (int j = 0; j < 4; ++j) {
      int n = n0 + wc + j * 16 + r15;
      float bv = bias[n];
#pragma unroll
      for (int r = 0; r < 4; ++r) {
        int m = m0 + wr + i * 16 + rbase + r;
        float val = acc[i][j][r] + bv;
        if (MODE == 0) {
          int h = n / 192, rem = n % 192;
          int part = rem >> 6, d = rem & 63;
          int b = m >> 11, s = m & 2047;
          int off = (((b * 16 + h) * 2048) + s) * 64 + d;
          // q folded scale: 0.125 * log2(e) so attention can use exp2 directly
          u16 hv = f2b(part == 0 ? val * 0.180336880111f : val);
          if (part == 0) Qo[off] = hv;
          else if (part == 1) Ko[off] = hv;
          else Vo[off] = hv;
        } else {
          outf[m * 1024 + n] = val;
        }
      }
    }
}

// ---------------- flash attention ----------------
// 1D grid 1024, XCD remap: xcd=bid&7, qb=(bid>>3)&15, bh=xcd*8+(bid>>7) (K/V L2-resident).
// 4 waves, 128 q/block (32/wave as 2 q-frags). Swapped QK^T (16x16x32). PV via
// mfma_f32_16x16x16bf16_1k: QK^T C/D row layout (4g+j) == 16x16x16 A-operand k
// layout (4g+e), so each lane's own exp'd scores (cvtpk-packed, s_nop-padded)
// ARE the PV A-frag -> NO P LDS round-trip. V^T [d][kv] in LDS with 4-elem-chunk
// XOR swizzle swz4(d)=((d>>3)^d)&15: conflict-free scalar transpose-writes AND
// b64 B-frag reads. K [kv][64] XOR-swizzled via pre-swizzled global_load_lds
// source. LDS 32KB -> 4 blocks/CU. Double-buffered, 1 barrier/tile, T14 split.
__global__ __launch_bounds__(256, 4) void attn_fwd(const u16* __restrict__ Q,
                                                   const u16* __restrict__ K,
                                                   const u16* __restrict__ V,
                                                   u16* __restrict__ O) {
  __shared__ u16 lds[16384];  // [0,8192): K dbuf, [8192,16384): V^T dbuf
  int tid = threadIdx.x;
  int l = tid & 63, w = tid >> 6;
  int g = l >> 4, r15 = l & 15, r7 = r15 & 7;
  int bid = blockIdx.x;
  int qb = (bid >> 3) & 15;
  int bh = (bid & 7) * 8 + (bid >> 7);
  const u16* Kb = K + bh * 131072;
  const u16* Vb = V + bh * 131072;
  int ka = g * 8;
  int qbase = qb * 128 + w * 32;
  U4B8 t0, t1, t2, t3;
  t0.u = *(const uint4*)(Q + bh * 131072 + (qbase + r15) * 64 + ka);
  t1.u = *(const uint4*)(Q + bh * 131072 + (qbase + r15) * 64 + 32 + ka);
  t2.u = *(const uint4*)(Q + bh * 131072 + (qbase + 16 + r15) * 64 + ka);
  t3.u = *(const uint4*)(Q + bh * 131072 + (qbase + 16 + r15) * 64 + 32 + ka);
  bf16x8 qf00 = t0.v, qf01 = t1.v, qf10 = t2.v, qf11 = t3.v;

  // K b128 read addrs: row=c*16+r15, chunk (g)^(row&7)
  int kaddr[4];
#pragma unroll
  for (int c = 0; c < 4; ++c) kaddr[c] = (c * 16 + r15) * 64 + ((g ^ r7) << 3);
  // V^T b64 read components: d = r15+16dq; addr = 8192 + d*64 + (((4c+g)^vsw)<<2)
  int vrow[4], vsw[4];
#pragma unroll
  for (int dq = 0; dq < 4; ++dq) {
    int d = r15 + 16 * dq;
    vrow[dq] = 8192 + d * 64;
    vsw[dq] = ((d >> 3) ^ d) & 15;
  }

  // K staging via global_load_lds, source chunk pre-swizzled (m173 pattern)
  int krow0 = tid >> 3;
  int kcg = (((tid & 7) ^ (krow0 & 7)) << 3);
  // V staging: thread loads V[sr0][sdg..sdg+7] (+32 rows), scatters transposed+swizzled
  int sr0 = tid >> 3, sdgi = tid & 7, sdg = sdgi * 8;
  int vwa[16];
#pragma unroll
  for (int i = 0; i < 8; ++i) {
    int d = sdg + i;
    int sw = ((d >> 3) ^ d) & 15;
    vwa[2 * i] = d * 64 + ((((sr0 >> 2)) ^ sw) << 2) + (sr0 & 3);
    vwa[2 * i + 1] = d * 64 + ((((sr0 >> 2) + 8) ^ sw) << 2) + (sr0 & 3);
  }
  U4B8 vreg[2];

#define STAGE(OFFW, TN)                                                                    \
  {                                                                                        \
    int kv0 = (TN) * 64;                                                                   \
    __builtin_amdgcn_global_load_lds(                                                      \
        (const __attribute__((address_space(1))) void*)(Kb + (kv0 + krow0) * 64 + kcg),    \
        (__attribute__((address_space(3))) void*)(&lds[(OFFW) + tid * 8]), 16, 0, 0);      \
    __builtin_amdgcn_global_load_lds(                                                      \
        (const __attribute__((address_space(1))) void*)(Kb + (kv0 + krow0 + 32) * 64 + kcg), \
        (__attribute__((address_space(3))) void*)(&lds[(OFFW) + 2048 + tid * 8]), 16, 0, 0); \
    vreg[0].u = *(const uint4*)(Vb + (kv0 + sr0) * 64 + sdg);                              \
    vreg[1].u = *(const uint4*)(Vb + (kv0 + sr0 + 32) * 64 + sdg);                         \
  }

#define WRITEV(OFFW)                                                                       \
  {                                                                                        \
    _Pragma("unroll") for (int i = 0; i < 8; ++i) {                                        \
      lds[8192 + (OFFW) + vwa[2 * i]] = vreg[0].s[i];                                      \
      lds[8192 + (OFFW) + vwa[2 * i + 1]] = vreg[1].s[i];                                  \
    }                                                                                      \
  }

  float l0 = 0.f, l1 = 0.f;
  f32x4 o0[4] = {}, o1[4] = {};

#define COMPUTE(OFFR)                                                                      \
  {                                                                                        \
    _Pragma("unroll") for (int c = 0; c < 4; ++c) {                                        \
      U4B8 k0, k1;                                                                         \
      k0.u = *(const uint4*)(&lds[(OFFR) + kaddr[c]]);                                     \
      k1.u = *(const uint4*)(&lds[(OFFR) + (kaddr[c] ^ 32)]);                              \
      f32x4 z0 = {}, z1 = {};                                                              \
      z0 = __builtin_amdgcn_mfma_f32_16x16x32_bf16(k0.v, qf00, z0, 0, 0, 0);               \
      z0 = __builtin_amdgcn_mfma_f32_16x16x32_bf16(k1.v, qf01, z0, 0, 0, 0);               \
      z1 = __builtin_amdgcn_mfma_f32_16x16x32_bf16(k0.v, qf10, z1, 0, 0, 0);               \
      z1 = __builtin_amdgcn_mfma_f32_16x16x32_bf16(k1.v, qf11, z1, 0, 0, 0);               \
      float a0 = exp2f(z0[0]), a1 = exp2f(z0[1]), a2 = exp2f(z0[2]), a3 = exp2f(z0[3]);    \
      l0 += (a0 + a1) + (a2 + a3);                                                         \
      U2S4 pa0; pa0.u2.x = cvtpk(a0, a1); pa0.u2.y = cvtpk(a2, a3);                        \
      float b0 = exp2f(z1[0]), b1 = exp2f(z1[1]), b2 = exp2f(z1[2]), b3 = exp2f(z1[3]);    \
      l1 += (b0 + b1) + (b2 + b3);                                                         \
      U2S4 pa1; pa1.u2.x = cvtpk(b0, b1); pa1.u2.y = cvtpk(b2, b3);                        \
      _Pragma("unroll") for (int dq = 0; dq < 4; ++dq) {                                   \
        U2S4 vb;                                                                           \
        vb.u2 = *(const uint2*)(&lds[(OFFR) + vrow[dq] + (((4 * c + g) ^ vsw[dq]) << 2)]); \
        o0[dq] = __builtin_amdgcn_mfma_f32_16x16x16bf16_1k(pa0.s, vb.s, o0[dq], 0, 0, 0);  \
        o1[dq] = __builtin_amdgcn_mfma_f32_16x16x16bf16_1k(pa1.s, vb.s, o1[dq], 0, 0, 0);  \
      }                                                                                    \
    }                                                                                      \
  }

  STAGE(0, 0);
  WRITEV(0);
#pragma unroll 1
  for (int tt = 0; tt < 16; ++tt) {
    __syncthreads();
    STAGE(4096, 2 * tt + 1);
    COMPUTE(0);
    WRITEV(4096);
    __syncthreads();
    if (tt < 15) STAGE(0, 2 * tt + 2);
    COMPUTE(4096);
    if (tt < 15) WRITEV(0);
  }
#undef STAGE
#undef WRITEV
#undef COMPUTE

  l0 += __shfl_xor(l0, 16); l0 += __shfl_xor(l0, 32);
  l1 += __shfl_xor(l1, 16); l1 += __shfl_xor(l1, 32);
  float i0 = 1.f / l0, i1 = 1.f / l1;
  float c0[4], c1[4];
#pragma unroll
  for (int j = 0; j < 4; ++j) {
    c0[j] = __shfl(i0, 4 * g + j);
    c1[j] = __shfl(i1, 4 * g + j);
  }
  // ---- staged O epilogue: per-wave 32x64 bf16 tile in reused LDS -> full-line stores ----
  __syncthreads();   // all waves done reading K/V buffers before reuse
  u16* stg = lds + w * 2048;
#pragma unroll
  for (int j = 0; j < 4; ++j) {
    int rr0 = 4 * g + j;        // (rr0>>2)&3 == g
    int rr1 = 16 + 4 * g + j;   // (rr1>>2)&3 == g
#pragma unroll
    for (int dq = 0; dq < 4; ++dq) {
      int pc = ((dq ^ g) << 4) + r15;
      stg[rr0 * 64 + pc] = f2b(o0[dq][j] * c0[j]);
      stg[rr1 * 64 + pc] = f2b(o1[dq][j] * c1[j]);
    }
  }
  int b = bh >> 4, h = bh & 15;
  int colpair = (l & 31) * 2;
  int rowsel = l >> 5;
#pragma unroll
  for (int it = 0; it < 16; ++it) {
    int rr = 2 * it + rowsel;
    int phys = rr * 64 + (((colpair >> 4) ^ ((rr >> 2) & 3)) << 4) + (colpair & 15);
    unsigned pv = *(const unsigned*)(&stg[phys]);
    int row = qbase + rr;
    *(unsigned*)(&O[(b * 2048 + row) * 1024 + h * 64 + colpair]) = pv;
  }
}

extern "C" void kernel_launch(void* const* d_in, const int* in_sizes, int n_in,
                              void* d_out, int out_size, void* d_ws, size_t ws_size,
                              hipStream_t stream) {
  const float* x = (const float*)d_in[0];
  const float* Wqkv = (const float*)d_in[1];
  const float* bqkv = (const float*)d_in[2];
  const float* Wout = (const float*)d_in[3];
  const float* bout = (const float*)d_in[4];
  float* out = (float*)d_out;

  u16* ws = (u16*)d_ws;
  u16* WtQ = ws;                    // 3072*1024
  u16* WtO = WtQ + 3072 * 1024;     // 1024*1024
  u16* Xb  = WtO + 1024 * 1024;     // 8192*1024
  u16* Qw  = Xb + 8192 * 1024;      // 64*2048*64
  u16* Kw  = Qw + 64 * 2048 * 64;
  u16* Vw  = Kw + 64 * 2048 * 64;
  u16* Aw  = Vw + 64 * 2048 * 64;   // 8192*1024

  cvt_f32_bf16<<<8192, 256, 0, stream>>>(x, Xb);
  transpose_w<<<dim3(48, 16), 256, 0, stream>>>(Wqkv, WtQ, 1024, 3072);
  transpose_w<<<dim3(16, 16), 256, 0, stream>>>(Wout, WtO, 1024, 1024);
  gemm_bf16<0><<<dim3(24, 64), 256, 0, stream>>>(Xb, WtQ, bqkv, nullptr, Qw, Kw, Vw);
  attn_fwd<<<1024, 256, 0, stream>>>(Qw, Kw, Vw, Aw);
  gemm_bf16<1><<<dim3(8, 64), 256, 0, stream>>>(Aw, WtO, bout, out, nullptr, nullptr, nullptr);
}

// Round 8
// 251.913 us; speedup vs baseline: 1.7643x; 1.7643x over previous
//
#include <hip/hip_runtime.h>

typedef unsigned short u16;
typedef __bf16 bf16x8 __attribute__((ext_vector_type(8)));
typedef short s16x4 __attribute__((ext_vector_type(4)));
typedef float f32x4 __attribute__((ext_vector_type(4)));

union U4B8 { uint4 u; bf16x8 v; u16 s[8]; };
union U2S4 { uint2 u2; s16x4 s; };

__device__ __forceinline__ u16 f2b(float f) {
  union { float f; unsigned u; } x; x.f = f;
  unsigned u = x.u + 0x7fffu + ((x.u >> 16) & 1u);
  return (u16)(u >> 16);
}

// 2x bf16 pack. s_nop 3 embedded: the result feeds MFMA SrcA directly; the
// VALU-write->MFMA-read hazard wait-states can't be inserted by the compiler
// for an inline-asm producer (round-3/round-6 lesson), so we carry them here.
__device__ __forceinline__ unsigned cvtpk(float lo, float hi) {
  unsigned r;
  asm("v_cvt_pk_bf16_f32 %0, %1, %2\n\ts_nop 3" : "=v"(r) : "v"(lo), "v"(hi));
  return r;
}

// ---------------- fp32 -> bf16 elementwise (for x) ----------------
__global__ __launch_bounds__(256) void cvt_f32_bf16(const float* __restrict__ in,
                                                    u16* __restrict__ out) {
  int i = blockIdx.x * 256 + threadIdx.x;
  float4 v = ((const float4*)in)[i];
  ushort4 h;
  h.x = f2b(v.x); h.y = f2b(v.y); h.z = f2b(v.z); h.w = f2b(v.w);
  ((ushort4*)out)[i] = h;
}

// ---------------- W [K][N] fp32 -> Wt [N][K] bf16 ----------------
__global__ __launch_bounds__(256) void transpose_w(const float* __restrict__ in,
                                                   u16* __restrict__ out, int K, int N) {
  __shared__ u16 t[64 * 72];
  int k0 = blockIdx.y * 64, n0 = blockIdx.x * 64;
  int tid = threadIdx.x;
#pragma unroll
  for (int p = 0; p < 4; ++p) {
    int idx = p * 256 + tid;
    int k = idx >> 4, ng = idx & 15;
    float4 v = *(const float4*)(in + (k0 + k) * N + n0 + ng * 4);
    t[(ng * 4 + 0) * 72 + k] = f2b(v.x);
    t[(ng * 4 + 1) * 72 + k] = f2b(v.y);
    t[(ng * 4 + 2) * 72 + k] = f2b(v.z);
    t[(ng * 4 + 3) * 72 + k] = f2b(v.w);
  }
  __syncthreads();
#pragma unroll
  for (int p = 0; p < 2; ++p) {
    int idx = p * 256 + tid;
    int n = idx >> 3, kg = (idx & 7) * 8;
    uint4 u = *(uint4*)(&t[n * 72 + kg]);
    *(uint4*)(out + (n0 + n) * K + k0 + kg) = u;
  }
}

// ---------------- GEMM: C[M][N] = A[M][1024] @ Wt^T + bias ----------------
// MODE 0: N=3072, out -> Q/K/V bf16 [64][2048][64], q scaled by 0.125*log2(e)
// MODE 1: N=1024, out -> fp32 d_out
template <int MODE>
__global__ __launch_bounds__(256) void gemm_bf16(const u16* __restrict__ A,
                                                 const u16* __restrict__ B,
                                                 const float* __restrict__ bias,
                                                 float* __restrict__ outf,
                                                 u16* __restrict__ Qo, u16* __restrict__ Ko,
                                                 u16* __restrict__ Vo) {
  __shared__ u16 a_lds[128 * 32];
  __shared__ u16 b_lds[128 * 32];
  int tid = threadIdx.x;
  int l = tid & 63, w = tid >> 6;
  int wr = (w >> 1) * 64, wc = (w & 1) * 64;
  int m0 = blockIdx.y * 128, n0 = blockIdx.x * 128;
  int r15 = l & 15;
  int ka = (l >> 4) * 8;
  int r0 = tid >> 2, kg0 = (tid & 3) * 8;
  f32x4 acc[4][4] = {};
  for (int kt = 0; kt < 32; ++kt) {
    int k0 = kt * 32;
    __syncthreads();
    __builtin_amdgcn_global_load_lds(
        (const __attribute__((address_space(1))) void*)(A + (m0 + r0) * 1024 + k0 + kg0),
        (__attribute__((address_space(3))) void*)(&a_lds[tid * 8]), 16, 0, 0);
    __builtin_amdgcn_global_load_lds(
        (const __attribute__((address_space(1))) void*)(A + (m0 + 64 + r0) * 1024 + k0 + kg0),
        (__attribute__((address_space(3))) void*)(&a_lds[2048 + tid * 8]), 16, 0, 0);
    __builtin_amdgcn_global_load_lds(
        (const __attribute__((address_space(1))) void*)(B + (n0 + r0) * 1024 + k0 + kg0),
        (__attribute__((address_space(3))) void*)(&b_lds[tid * 8]), 16, 0, 0);
    __builtin_amdgcn_global_load_lds(
        (const __attribute__((address_space(1))) void*)(B + (n0 + 64 + r0) * 1024 + k0 + kg0),
        (__attribute__((address_space(3))) void*)(&b_lds[2048 + tid * 8]), 16, 0, 0);
    __syncthreads();
    bf16x8 af[4], bf[4];
#pragma unroll
    for (int i = 0; i < 4; ++i) {
      U4B8 ua; ua.u = *(uint4*)(&a_lds[(wr + i * 16 + r15) * 32 + ka]); af[i] = ua.v;
      U4B8 ub; ub.u = *(uint4*)(&b_lds[(wc + i * 16 + r15) * 32 + ka]); bf[i] = ub.v;
    }
#pragma unroll
    for (int i = 0; i < 4; ++i)
#pragma unroll
      for (int j = 0; j < 4; ++j)
        acc[i][j] = __builtin_amdgcn_mfma_f32_16x16x32_bf16(af[i], bf[j], acc[i][j], 0, 0, 0);
  }
  int rbase = (l >> 4) * 4;
#pragma unroll
  for (int i = 0; i < 4; ++i)
#pragma unroll
    for (int j = 0; j < 4; ++j) {
      int n = n0 + wc + j * 16 + r15;
      float bv = bias[n];
#pragma unroll
      for (int r = 0; r < 4; ++r) {
        int m = m0 + wr + i * 16 + rbase + r;
        float val = acc[i][j][r] + bv;
        if (MODE == 0) {
          int h = n / 192, rem = n % 192;
          int part = rem >> 6, d = rem & 63;
          int b = m >> 11, s = m & 2047;
          int off = (((b * 16 + h) * 2048) + s) * 64 + d;
          // q folded scale: 0.125 * log2(e) so attention can use exp2 directly
          u16 hv = f2b(part == 0 ? val * 0.180336880111f : val);
          if (part == 0) Qo[off] = hv;
          else if (part == 1) Ko[off] = hv;
          else Vo[off] = hv;
        } else {
          outf[m * 1024 + n] = val;
        }
      }
    }
}

// ---------------- flash attention ----------------
// 1D grid 1024, XCD remap: xcd=bid&7, qb=(bid>>3)&15, bh=xcd*8+(bid>>7) (K/V L2-resident).
// 4 waves, 128 q/block (32/wave as 2 q-frags). Swapped QK^T (16x16x32). PV via
// mfma_f32_16x16x16bf16_1k: QK^T C/D row layout (4g+j) == 16x16x16 A-operand k
// layout (4g+e), so each lane's own exp'd scores (cvtpk-packed, s_nop-padded)
// ARE the PV A-frag -> NO P LDS round-trip. V^T [d][kv] in LDS with 4-elem-chunk
// XOR swizzle swz4(d)=((d>>3)^d)&15: conflict-free scalar transpose-writes AND
// b64 B-frag reads. K [kv][64] XOR-swizzled via pre-swizzled global_load_lds
// source. LDS 32KB. Double-buffered, 1 barrier/tile, T14 split.
// launch_bounds (256,2): round-7's (256,4) forced VGPR=64 -> ~900MB scratch
// spill traffic (FETCH 646MB/WRITE 322MB). Cap 256 VGPR; HW still co-schedules
// ~4 waves/SIMD at the natural ~112-VGPR allocation.
__global__ __launch_bounds__(256, 2) void attn_fwd(const u16* __restrict__ Q,
                                                   const u16* __restrict__ K,
                                                   const u16* __restrict__ V,
                                                   u16* __restrict__ O) {
  __shared__ u16 lds[16384];  // [0,8192): K dbuf, [8192,16384): V^T dbuf
  int tid = threadIdx.x;
  int l = tid & 63, w = tid >> 6;
  int g = l >> 4, r15 = l & 15, r7 = r15 & 7;
  int bid = blockIdx.x;
  int qb = (bid >> 3) & 15;
  int bh = (bid & 7) * 8 + (bid >> 7);
  const u16* Kb = K + bh * 131072;
  const u16* Vb = V + bh * 131072;
  int ka = g * 8;
  int qbase = qb * 128 + w * 32;
  U4B8 t0, t1, t2, t3;
  t0.u = *(const uint4*)(Q + bh * 131072 + (qbase + r15) * 64 + ka);
  t1.u = *(const uint4*)(Q + bh * 131072 + (qbase + r15) * 64 + 32 + ka);
  t2.u = *(const uint4*)(Q + bh * 131072 + (qbase + 16 + r15) * 64 + ka);
  t3.u = *(const uint4*)(Q + bh * 131072 + (qbase + 16 + r15) * 64 + 32 + ka);
  bf16x8 qf00 = t0.v, qf01 = t1.v, qf10 = t2.v, qf11 = t3.v;

  // K b128 read addrs: row=c*16+r15, chunk (g)^(row&7)
  int kaddr[4];
#pragma unroll
  for (int c = 0; c < 4; ++c) kaddr[c] = (c * 16 + r15) * 64 + ((g ^ r7) << 3);
  // V^T b64 read components: d = r15+16dq; addr = 8192 + d*64 + (((4c+g)^vsw)<<2)
  int vrow[4], vsw[4];
#pragma unroll
  for (int dq = 0; dq < 4; ++dq) {
    int d = r15 + 16 * dq;
    vrow[dq] = 8192 + d * 64;
    vsw[dq] = ((d >> 3) ^ d) & 15;
  }

  // K staging via global_load_lds, source chunk pre-swizzled (m173 pattern)
  int krow0 = tid >> 3;
  int kcg = (((tid & 7) ^ (krow0 & 7)) << 3);
  // V staging: thread loads V[sr0][sdg..sdg+7] (+32 rows), scatters transposed+swizzled
  int sr0 = tid >> 3, sdgi = tid & 7, sdg = sdgi * 8;
  U4B8 vreg[2];

#define STAGE(OFFW, TN)                                                                    \
  {                                                                                        \
    int kv0 = (TN) * 64;                                                                   \
    __builtin_amdgcn_global_load_lds(                                                      \
        (const __attribute__((address_space(1))) void*)(Kb + (kv0 + krow0) * 64 + kcg),    \
        (__attribute__((address_space(3))) void*)(&lds[(OFFW) + tid * 8]), 16, 0, 0);      \
    __builtin_amdgcn_global_load_lds(                                                      \
        (const __attribute__((address_space(1))) void*)(Kb + (kv0 + krow0 + 32) * 64 + kcg), \
        (__attribute__((address_space(3))) void*)(&lds[(OFFW) + 2048 + tid * 8]), 16, 0, 0); \
    vreg[0].u = *(const uint4*)(Vb + (kv0 + sr0) * 64 + sdg);                              \
    vreg[1].u = *(const uint4*)(Vb + (kv0 + sr0 + 32) * 64 + sdg);                         \
  }

  // V write addresses recomputed inline (cheap VALU) instead of a vwa[16]
  // array held live across the whole K-loop (register-pressure shed).
#define WRITEV(OFFW)                                                                       \
  {                                                                                        \
    _Pragma("unroll") for (int i = 0; i < 8; ++i) {                                        \
      int d = sdg + i;                                                                     \
      int sw = ((d >> 3) ^ d) & 15;                                                        \
      lds[8192 + (OFFW) + d * 64 + (((sr0 >> 2) ^ sw) << 2) + (sr0 & 3)] = vreg[0].s[i];   \
      lds[8192 + (OFFW) + d * 64 + ((((sr0 >> 2) + 8) ^ sw) << 2) + (sr0 & 3)] =           \
          vreg[1].s[i];                                                                    \
    }                                                                                      \
  }

  float l0 = 0.f, l1 = 0.f;
  f32x4 o0[4] = {}, o1[4] = {};

#define COMPUTE(OFFR)                                                                      \
  {                                                                                        \
    _Pragma("unroll") for (int c = 0; c < 4; ++c) {                                        \
      U4B8 k0, k1;                                                                         \
      k0.u = *(const uint4*)(&lds[(OFFR) + kaddr[c]]);                                     \
      k1.u = *(const uint4*)(&lds[(OFFR) + (kaddr[c] ^ 32)]);                              \
      f32x4 z0 = {}, z1 = {};                                                              \
      z0 = __builtin_amdgcn_mfma_f32_16x16x32_bf16(k0.v, qf00, z0, 0, 0, 0);               \
      z0 = __builtin_amdgcn_mfma_f32_16x16x32_bf16(k1.v, qf01, z0, 0, 0, 0);               \
      z1 = __builtin_amdgcn_mfma_f32_16x16x32_bf16(k0.v, qf10, z1, 0, 0, 0);               \
      z1 = __builtin_amdgcn_mfma_f32_16x16x32_bf16(k1.v, qf11, z1, 0, 0, 0);               \
      float a0 = exp2f(z0[0]), a1 = exp2f(z0[1]), a2 = exp2f(z0[2]), a3 = exp2f(z0[3]);    \
      l0 += (a0 + a1) + (a2 + a3);                                                         \
      U2S4 pa0; pa0.u2.x = cvtpk(a0, a1); pa0.u2.y = cvtpk(a2, a3);                        \
      float b0 = exp2f(z1[0]), b1 = exp2f(z1[1]), b2 = exp2f(z1[2]), b3 = exp2f(z1[3]);    \
      l1 += (b0 + b1) + (b2 + b3);                                                         \
      U2S4 pa1; pa1.u2.x = cvtpk(b0, b1); pa1.u2.y = cvtpk(b2, b3);                        \
      _Pragma("unroll") for (int dq = 0; dq < 4; ++dq) {                                   \
        U2S4 vb;                                                                           \
        vb.u2 = *(const uint2*)(&lds[(OFFR) + vrow[dq] + (((4 * c + g) ^ vsw[dq]) << 2)]); \
        o0[dq] = __builtin_amdgcn_mfma_f32_16x16x16bf16_1k(pa0.s, vb.s, o0[dq], 0, 0, 0);  \
        o1[dq] = __builtin_amdgcn_mfma_f32_16x16x16bf16_1k(pa1.s, vb.s, o1[dq], 0, 0, 0);  \
      }                                                                                    \
    }                                                                                      \
  }

  STAGE(0, 0);
  WRITEV(0);
#pragma unroll 1
  for (int tt = 0; tt < 16; ++tt) {
    __syncthreads();
    STAGE(4096, 2 * tt + 1);
    COMPUTE(0);
    WRITEV(4096);
    __syncthreads();
    if (tt < 15) STAGE(0, 2 * tt + 2);
    COMPUTE(4096);
    if (tt < 15) WRITEV(0);
  }
#undef STAGE
#undef WRITEV
#undef COMPUTE

  l0 += __shfl_xor(l0, 16); l0 += __shfl_xor(l0, 32);
  l1 += __shfl_xor(l1, 16); l1 += __shfl_xor(l1, 32);
  float i0 = 1.f / l0, i1 = 1.f / l1;
  float c0[4], c1[4];
#pragma unroll
  for (int j = 0; j < 4; ++j) {
    c0[j] = __shfl(i0, 4 * g + j);
    c1[j] = __shfl(i1, 4 * g + j);
  }
  // ---- staged O epilogue: per-wave 32x64 bf16 tile in reused LDS -> full-line stores ----
  __syncthreads();   // all waves done reading K/V buffers before reuse
  u16* stg = lds + w * 2048;
#pragma unroll
  for (int j = 0; j < 4; ++j) {
    int rr0 = 4 * g + j;        // (rr0>>2)&3 == g
    int rr1 = 16 + 4 * g + j;   // (rr1>>2)&3 == g
#pragma unroll
    for (int dq = 0; dq < 4; ++dq) {
      int pc = ((dq ^ g) << 4) + r15;
      stg[rr0 * 64 + pc] = f2b(o0[dq][j] * c0[j]);
      stg[rr1 * 64 + pc] = f2b(o1[dq][j] * c1[j]);
    }
  }
  int b = bh >> 4, h = bh & 15;
  int colpair = (l & 31) * 2;
  int rowsel = l >> 5;
#pragma unroll
  for (int it = 0; it < 16; ++it) {
    int rr = 2 * it + rowsel;
    int phys = rr * 64 + (((colpair >> 4) ^ ((rr >> 2) & 3)) << 4) + (colpair & 15);
    unsigned pv = *(const unsigned*)(&stg[phys]);
    int row = qbase + rr;
    *(unsigned*)(&O[(b * 2048 + row) * 1024 + h * 64 + colpair]) = pv;
  }
}

extern "C" void kernel_launch(void* const* d_in, const int* in_sizes, int n_in,
                              void* d_out, int out_size, void* d_ws, size_t ws_size,
                              hipStream_t stream) {
  const float* x = (const float*)d_in[0];
  const float* Wqkv = (const float*)d_in[1];
  const float* bqkv = (const float*)d_in[2];
  const float* Wout = (const float*)d_in[3];
  const float* bout = (const float*)d_in[4];
  float* out = (float*)d_out;

  u16* ws = (u16*)d_ws;
  u16* WtQ = ws;                    // 3072*1024
  u16* WtO = WtQ + 3072 * 1024;     // 1024*1024
  u16* Xb  = WtO + 1024 * 1024;     // 8192*1024
  u16* Qw  = Xb + 8192 * 1024;      // 64*2048*64
  u16* Kw  = Qw + 64 * 2048 * 64;
  u16* Vw  = Kw + 64 * 2048 * 64;
  u16* Aw  = Vw + 64 * 2048 * 64;   // 8192*1024

  cvt_f32_bf16<<<8192, 256, 0, stream>>>(x, Xb);
  transpose_w<<<dim3(48, 16), 256, 0, stream>>>(Wqkv, WtQ, 1024, 3072);
  transpose_w<<<dim3(16, 16), 256, 0, stream>>>(Wout, WtO, 1024, 1024);
  gemm_bf16<0><<<dim3(24, 64), 256, 0, stream>>>(Xb, WtQ, bqkv, nullptr, Qw, Kw, Vw);
  attn_fwd<<<1024, 256, 0, stream>>>(Qw, Kw, Vw, Aw);
  gemm_bf16<1><<<dim3(8, 64), 256, 0, stream>>>(Aw, WtO, bout, out, nullptr, nullptr, nullptr);
}

// Round 9
// 218.562 us; speedup vs baseline: 2.0335x; 1.1526x over previous
//
#include <hip/hip_runtime.h>

typedef unsigned short u16;
typedef __bf16 bf16x8 __attribute__((ext_vector_type(8)));
typedef __bf16 bf16x4 __attribute__((ext_vector_type(4)));
typedef short s16x4 __attribute__((ext_vector_type(4)));
typedef float f32x4 __attribute__((ext_vector_type(4)));

union U4B8 { uint4 u; bf16x8 v; u16 s[8]; };
union U2S4 { uint2 u2; s16x4 s; bf16x4 h; };

__device__ __forceinline__ u16 f2b(float f) {
  union { float f; unsigned u; } x; x.f = f;
  unsigned u = x.u + 0x7fffu + ((x.u >> 16) & 1u);
  return (u16)(u >> 16);
}

// ---------------- fp32 -> bf16 elementwise (for x) ----------------
__global__ __launch_bounds__(256) void cvt_f32_bf16(const float* __restrict__ in,
                                                    u16* __restrict__ out) {
  int i = blockIdx.x * 256 + threadIdx.x;
  float4 v = ((const float4*)in)[i];
  ushort4 h;
  h.x = f2b(v.x); h.y = f2b(v.y); h.z = f2b(v.z); h.w = f2b(v.w);
  ((ushort4*)out)[i] = h;
}

// ---------------- W [K][N] fp32 -> Wt [N][K] bf16 ----------------
__global__ __launch_bounds__(256) void transpose_w(const float* __restrict__ in,
                                                   u16* __restrict__ out, int K, int N) {
  __shared__ u16 t[64 * 72];
  int k0 = blockIdx.y * 64, n0 = blockIdx.x * 64;
  int tid = threadIdx.x;
#pragma unroll
  for (int p = 0; p < 4; ++p) {
    int idx = p * 256 + tid;
    int k = idx >> 4, ng = idx & 15;
    float4 v = *(const float4*)(in + (k0 + k) * N + n0 + ng * 4);
    t[(ng * 4 + 0) * 72 + k] = f2b(v.x);
    t[(ng * 4 + 1) * 72 + k] = f2b(v.y);
    t[(ng * 4 + 2) * 72 + k] = f2b(v.z);
    t[(ng * 4 + 3) * 72 + k] = f2b(v.w);
  }
  __syncthreads();
#pragma unroll
  for (int p = 0; p < 2; ++p) {
    int idx = p * 256 + tid;
    int n = idx >> 3, kg = (idx & 7) * 8;
    uint4 u = *(uint4*)(&t[n * 72 + kg]);
    *(uint4*)(out + (n0 + n) * K + k0 + kg) = u;
  }
}

// ---------------- GEMM: C[M][N] = A[M][1024] @ Wt^T + bias ----------------
// MODE 0: N=3072, out -> Q/K/V bf16 [64][2048][64], q scaled by 0.125*log2(e)
// MODE 1: N=1024, out -> fp32 d_out
template <int MODE>
__global__ __launch_bounds__(256) void gemm_bf16(const u16* __restrict__ A,
                                                 const u16* __restrict__ B,
                                                 const float* __restrict__ bias,
                                                 float* __restrict__ outf,
                                                 u16* __restrict__ Qo, u16* __restrict__ Ko,
                                                 u16* __restrict__ Vo) {
  __shared__ u16 a_lds[128 * 32];
  __shared__ u16 b_lds[128 * 32];
  int tid = threadIdx.x;
  int l = tid & 63, w = tid >> 6;
  int wr = (w >> 1) * 64, wc = (w & 1) * 64;
  int m0 = blockIdx.y * 128, n0 = blockIdx.x * 128;
  int r15 = l & 15;
  int ka = (l >> 4) * 8;
  int r0 = tid >> 2, kg0 = (tid & 3) * 8;
  f32x4 acc[4][4] = {};
  for (int kt = 0; kt < 32; ++kt) {
    int k0 = kt * 32;
    __syncthreads();
    __builtin_amdgcn_global_load_lds(
        (const __attribute__((address_space(1))) void*)(A + (m0 + r0) * 1024 + k0 + kg0),
        (__attribute__((address_space(3))) void*)(&a_lds[tid * 8]), 16, 0, 0);
    __builtin_amdgcn_global_load_lds(
        (const __attribute__((address_space(1))) void*)(A + (m0 + 64 + r0) * 1024 + k0 + kg0),
        (__attribute__((address_space(3))) void*)(&a_lds[2048 + tid * 8]), 16, 0, 0);
    __builtin_amdgcn_global_load_lds(
        (const __attribute__((address_space(1))) void*)(B + (n0 + r0) * 1024 + k0 + kg0),
        (__attribute__((address_space(3))) void*)(&b_lds[tid * 8]), 16, 0, 0);
    __builtin_amdgcn_global_load_lds(
        (const __attribute__((address_space(1))) void*)(B + (n0 + 64 + r0) * 1024 + k0 + kg0),
        (__attribute__((address_space(3))) void*)(&b_lds[2048 + tid * 8]), 16, 0, 0);
    __syncthreads();
    bf16x8 af[4], bf[4];
#pragma unroll
    for (int i = 0; i < 4; ++i) {
      U4B8 ua; ua.u = *(uint4*)(&a_lds[(wr + i * 16 + r15) * 32 + ka]); af[i] = ua.v;
      U4B8 ub; ub.u = *(uint4*)(&b_lds[(wc + i * 16 + r15) * 32 + ka]); bf[i] = ub.v;
    }
#pragma unroll
    for (int i = 0; i < 4; ++i)
#pragma unroll
      for (int j = 0; j < 4; ++j)
        acc[i][j] = __builtin_amdgcn_mfma_f32_16x16x32_bf16(af[i], bf[j], acc[i][j], 0, 0, 0);
  }
  int rbase = (l >> 4) * 4;
#pragma unroll
  for (int i = 0; i < 4; ++i)
#pragma unroll
    for (int j = 0; j < 4; ++j) {
      int n = n0 + wc + j * 16 + r15;
      float bv = bias[n];
#pragma unroll
      for (int r = 0; r < 4; ++r) {
        int m = m0 + wr + i * 16 + rbase + r;
        float val = acc[i][j][r] + bv;
        if (MODE == 0) {
          int h = n / 192, rem = n % 192;
          int part = rem >> 6, d = rem & 63;
          int b = m >> 11, s = m & 2047;
          int off = (((b * 16 + h) * 2048) + s) * 64 + d;
          // q folded scale: 0.125 * log2(e) so attention can use exp2 directly
          u16 hv = f2b(part == 0 ? val * 0.180336880111f : val);
          if (part == 0) Qo[off] = hv;
          else if (part == 1) Ko[off] = hv;
          else Vo[off] = hv;
        } else {
          outf[m * 1024 + n] = val;
        }
      }
    }
}

// ---------------- flash attention ----------------
// 1D grid 1024, XCD remap: xcd=bid&7, qb=(bid>>3)&15, bh=xcd*8+(bid>>7) (K/V L2-resident).
// 4 waves, 128 q/block (32/wave as 2 q-frags). Swapped QK^T (16x16x32). PV via
// mfma_f32_16x16x16bf16_1k: lane's own exp'd scores (packed by COMPILER bf16
// casts -> pk-converts with correct MFMA hazards; m240: casts beat asm cvt_pk)
// are the PV A-frag -> no P LDS round-trip. exp2 via __builtin_amdgcn_exp2f
// (single v_exp_f32; libm exp2f lowers to a multi-op guarded sequence).
// V^T [d][kv] swz4(d)=((d>>3)^d)&15; write addrs precomputed vwa[8], 2nd write
// = vwa^32; read addr(c) = vaddr0 ^ (16c) (verified XOR algebra). K [kv][64]
// row&7-swizzled via pre-swizzled global_load_lds source. LDS 32KB, dbuf,
// 1 barrier/tile, T14 split. launch_bounds (256,2): (256,4) forced spills (r7).
__global__ __launch_bounds__(256, 2) void attn_fwd(const u16* __restrict__ Q,
                                                   const u16* __restrict__ K,
                                                   const u16* __restrict__ V,
                                                   u16* __restrict__ O) {
  __shared__ u16 lds[16384];  // [0,8192): K dbuf, [8192,16384): V^T dbuf
  int tid = threadIdx.x;
  int l = tid & 63, w = tid >> 6;
  int g = l >> 4, r15 = l & 15, r7 = r15 & 7;
  int bid = blockIdx.x;
  int qb = (bid >> 3) & 15;
  int bh = (bid & 7) * 8 + (bid >> 7);
  const u16* Kb = K + bh * 131072;
  const u16* Vb = V + bh * 131072;
  int ka = g * 8;
  int qbase = qb * 128 + w * 32;
  U4B8 t0, t1, t2, t3;
  t0.u = *(const uint4*)(Q + bh * 131072 + (qbase + r15) * 64 + ka);
  t1.u = *(const uint4*)(Q + bh * 131072 + (qbase + r15) * 64 + 32 + ka);
  t2.u = *(const uint4*)(Q + bh * 131072 + (qbase + 16 + r15) * 64 + ka);
  t3.u = *(const uint4*)(Q + bh * 131072 + (qbase + 16 + r15) * 64 + 32 + ka);
  bf16x8 qf00 = t0.v, qf01 = t1.v, qf10 = t2.v, qf11 = t3.v;

  // K b128 read addrs: row=c*16+r15, chunk (g)^(row&7); col+32 variant = ^32
  int kaddr[4];
#pragma unroll
  for (int c = 0; c < 4; ++c) kaddr[c] = (c * 16 + r15) * 64 + ((g ^ r7) << 3);
  // V^T b64 read base (c=0): d=16dq+r15; addr(c) = vaddr0 ^ (16c)
  int vaddr0[4];
#pragma unroll
  for (int dq = 0; dq < 4; ++dq) {
    int d = r15 + 16 * dq;
    int vsw = ((d >> 3) ^ d) & 15;
    vaddr0[dq] = 8192 + d * 64 + ((g ^ vsw) << 2);
  }

  // K staging via global_load_lds, source chunk pre-swizzled (m173 pattern)
  int krow0 = tid >> 3;
  int kcg = (((tid & 7) ^ (krow0 & 7)) << 3);
  // V staging write addrs precomputed: row pair (sr0, sr0+32) -> (vwa, vwa^32)
  int sr0 = tid >> 3, sdgi = tid & 7, sdg = sdgi * 8;
  int vwa[8];
#pragma unroll
  for (int i = 0; i < 8; ++i) {
    int d = sdg + i;
    int sw = ((d >> 3) ^ d) & 15;
    vwa[i] = 8192 + d * 64 + ((((sr0 >> 2)) ^ sw) << 2) + (sr0 & 3);
  }
  U4B8 vreg[2];

#define STAGE(OFFW, TN)                                                                    \
  {                                                                                        \
    int kv0 = (TN) * 64;                                                                   \
    __builtin_amdgcn_global_load_lds(                                                      \
        (const __attribute__((address_space(1))) void*)(Kb + (kv0 + krow0) * 64 + kcg),    \
        (__attribute__((address_space(3))) void*)(&lds[(OFFW) + tid * 8]), 16, 0, 0);      \
    __builtin_amdgcn_global_load_lds(                                                      \
        (const __attribute__((address_space(1))) void*)(Kb + (kv0 + krow0 + 32) * 64 + kcg), \
        (__attribute__((address_space(3))) void*)(&lds[(OFFW) + 2048 + tid * 8]), 16, 0, 0); \
    vreg[0].u = *(const uint4*)(Vb + (kv0 + sr0) * 64 + sdg);                              \
    vreg[1].u = *(const uint4*)(Vb + (kv0 + sr0 + 32) * 64 + sdg);                         \
  }

#define WRITEV(OFFW)                                                                       \
  {                                                                                        \
    _Pragma("unroll") for (int i = 0; i < 8; ++i) {                                        \
      lds[(OFFW) + vwa[i]] = vreg[0].s[i];                                                 \
      lds[(OFFW) + (vwa[i] ^ 32)] = vreg[1].s[i];                                          \
    }                                                                                      \
  }

  float l0 = 0.f, l1 = 0.f;
  f32x4 o0[4] = {}, o1[4] = {};

#define COMPUTE(OFFR)                                                                      \
  {                                                                                        \
    _Pragma("unroll") for (int c = 0; c < 4; ++c) {                                        \
      U4B8 k0, k1;                                                                         \
      k0.u = *(const uint4*)(&lds[(OFFR) + kaddr[c]]);                                     \
      k1.u = *(const uint4*)(&lds[(OFFR) + (kaddr[c] ^ 32)]);                              \
      f32x4 z0 = {}, z1 = {};                                                              \
      z0 = __builtin_amdgcn_mfma_f32_16x16x32_bf16(k0.v, qf00, z0, 0, 0, 0);               \
      z0 = __builtin_amdgcn_mfma_f32_16x16x32_bf16(k1.v, qf01, z0, 0, 0, 0);               \
      z1 = __builtin_amdgcn_mfma_f32_16x16x32_bf16(k0.v, qf10, z1, 0, 0, 0);               \
      z1 = __builtin_amdgcn_mfma_f32_16x16x32_bf16(k1.v, qf11, z1, 0, 0, 0);               \
      float a0 = __builtin_amdgcn_exp2f(z0[0]), a1 = __builtin_amdgcn_exp2f(z0[1]);        \
      float a2 = __builtin_amdgcn_exp2f(z0[2]), a3 = __builtin_amdgcn_exp2f(z0[3]);        \
      l0 += (a0 + a1) + (a2 + a3);                                                         \
      U2S4 pa0;                                                                            \
      pa0.h[0] = (__bf16)a0; pa0.h[1] = (__bf16)a1;                                        \
      pa0.h[2] = (__bf16)a2; pa0.h[3] = (__bf16)a3;                                        \
      float b0 = __builtin_amdgcn_exp2f(z1[0]), b1 = __builtin_amdgcn_exp2f(z1[1]);        \
      float b2 = __builtin_amdgcn_exp2f(z1[2]), b3 = __builtin_amdgcn_exp2f(z1[3]);        \
      l1 += (b0 + b1) + (b2 + b3);                                                         \
      U2S4 pa1;                                                                            \
      pa1.h[0] = (__bf16)b0; pa1.h[1] = (__bf16)b1;                                        \
      pa1.h[2] = (__bf16)b2; pa1.h[3] = (__bf16)b3;                                        \
      _Pragma("unroll") for (int dq = 0; dq < 4; ++dq) {                                   \
        U2S4 vb;                                                                           \
        vb.u2 = *(const uint2*)(&lds[(OFFR) + (vaddr0[dq] ^ (16 * c))]);                   \
        o0[dq] = __builtin_amdgcn_mfma_f32_16x16x16bf16_1k(pa0.s, vb.s, o0[dq], 0, 0, 0);  \
        o1[dq] = __builtin_amdgcn_mfma_f32_16x16x16bf16_1k(pa1.s, vb.s, o1[dq], 0, 0, 0);  \
      }                                                                                    \
    }                                                                                      \
  }

  STAGE(0, 0);
  WRITEV(0);
#pragma unroll 1
  for (int tt = 0; tt < 16; ++tt) {
    __syncthreads();
    STAGE(4096, 2 * tt + 1);
    COMPUTE(0);
    WRITEV(4096);
    __syncthreads();
    if (tt < 15) STAGE(0, 2 * tt + 2);
    COMPUTE(4096);
    if (tt < 15) WRITEV(0);
  }
#undef STAGE
#undef WRITEV
#undef COMPUTE

  l0 += __shfl_xor(l0, 16); l0 += __shfl_xor(l0, 32);
  l1 += __shfl_xor(l1, 16); l1 += __shfl_xor(l1, 32);
  float i0 = 1.f / l0, i1 = 1.f / l1;
  float c0[4], c1[4];
#pragma unroll
  for (int j = 0; j < 4; ++j) {
    c0[j] = __shfl(i0, 4 * g + j);
    c1[j] = __shfl(i1, 4 * g + j);
  }
  // ---- staged O epilogue: per-wave 32x64 bf16 tile in reused LDS -> full-line stores ----
  __syncthreads();   // all waves done reading K/V buffers before reuse
  u16* stg = lds + w * 2048;
#pragma unroll
  for (int j = 0; j < 4; ++j) {
    int rr0 = 4 * g + j;        // (rr0>>2)&3 == g
    int rr1 = 16 + 4 * g + j;   // (rr1>>2)&3 == g
#pragma unroll
    for (int dq = 0; dq < 4; ++dq) {
      int pc = ((dq ^ g) << 4) + r15;
      stg[rr0 * 64 + pc] = f2b(o0[dq][j] * c0[j]);
      stg[rr1 * 64 + pc] = f2b(o1[dq][j] * c1[j]);
    }
  }
  int b = bh >> 4, h = bh & 15;
  int colpair = (l & 31) * 2;
  int rowsel = l >> 5;
#pragma unroll
  for (int it = 0; it < 16; ++it) {
    int rr = 2 * it + rowsel;
    int phys = rr * 64 + (((colpair >> 4) ^ ((rr >> 2) & 3)) << 4) + (colpair & 15);
    unsigned pv = *(const unsigned*)(&stg[phys]);
    int row = qbase + rr;
    *(unsigned*)(&O[(b * 2048 + row) * 1024 + h * 64 + colpair]) = pv;
  }
}

extern "C" void kernel_launch(void* const* d_in, const int* in_sizes, int n_in,
                              void* d_out, int out_size, void* d_ws, size_t ws_size,
                              hipStream_t stream) {
  const float* x = (const float*)d_in[0];
  const float* Wqkv = (const float*)d_in[1];
  const float* bqkv = (const float*)d_in[2];
  const float* Wout = (const float*)d_in[3];
  const float* bout = (const float*)d_in[4];
  float* out = (float*)d_out;

  u16* ws = (u16*)d_ws;
  u16* WtQ = ws;                    // 3072*1024
  u16* WtO = WtQ + 3072 * 1024;     // 1024*1024
  u16* Xb  = WtO + 1024 * 1024;     // 8192*1024
  u16* Qw  = Xb + 8192 * 1024;      // 64*2048*64
  u16* Kw  = Qw + 64 * 2048 * 64;
  u16* Vw  = Kw + 64 * 2048 * 64;
  u16* Aw  = Vw + 64 * 2048 * 64;   // 8192*1024

  cvt_f32_bf16<<<8192, 256, 0, stream>>>(x, Xb);
  transpose_w<<<dim3(48, 16), 256, 0, stream>>>(Wqkv, WtQ, 1024, 3072);
  transpose_w<<<dim3(16, 16), 256, 0, stream>>>(Wout, WtO, 1024, 1024);
  gemm_bf16<0><<<dim3(24, 64), 256, 0, stream>>>(Xb, WtQ, bqkv, nullptr, Qw, Kw, Vw);
  attn_fwd<<<1024, 256, 0, stream>>>(Qw, Kw, Vw, Aw);
  gemm_bf16<1><<<dim3(8, 64), 256, 0, stream>>>(Aw, WtO, bout, out, nullptr, nullptr, nullptr);
}

// Round 10
// 212.538 us; speedup vs baseline: 2.0911x; 1.0283x over previous
//
#include <hip/hip_runtime.h>

typedef unsigned short u16;
typedef __bf16 bf16x8 __attribute__((ext_vector_type(8)));
typedef __bf16 bf16x4 __attribute__((ext_vector_type(4)));
typedef short s16x4 __attribute__((ext_vector_type(4)));
typedef float f32x4 __attribute__((ext_vector_type(4)));

union U4B8 { uint4 u; bf16x8 v; u16 s[8]; };
union U2S4 { uint2 u2; s16x4 s; bf16x4 h; };

__device__ __forceinline__ u16 f2b(float f) {
  union { float f; unsigned u; } x; x.f = f;
  unsigned u = x.u + 0x7fffu + ((x.u >> 16) & 1u);
  return (u16)(u >> 16);
}

// ---------------- fp32 -> bf16 elementwise (for x) ----------------
__global__ __launch_bounds__(256) void cvt_f32_bf16(const float* __restrict__ in,
                                                    u16* __restrict__ out) {
  int i = blockIdx.x * 256 + threadIdx.x;
  float4 v = ((const float4*)in)[i];
  ushort4 h;
  h.x = f2b(v.x); h.y = f2b(v.y); h.z = f2b(v.z); h.w = f2b(v.w);
  ((ushort4*)out)[i] = h;
}

// ---------------- W [K][N] fp32 -> Wt [N][K] bf16 ----------------
__global__ __launch_bounds__(256) void transpose_w(const float* __restrict__ in,
                                                   u16* __restrict__ out, int K, int N) {
  __shared__ u16 t[64 * 72];
  int k0 = blockIdx.y * 64, n0 = blockIdx.x * 64;
  int tid = threadIdx.x;
#pragma unroll
  for (int p = 0; p < 4; ++p) {
    int idx = p * 256 + tid;
    int k = idx >> 4, ng = idx & 15;
    float4 v = *(const float4*)(in + (k0 + k) * N + n0 + ng * 4);
    t[(ng * 4 + 0) * 72 + k] = f2b(v.x);
    t[(ng * 4 + 1) * 72 + k] = f2b(v.y);
    t[(ng * 4 + 2) * 72 + k] = f2b(v.z);
    t[(ng * 4 + 3) * 72 + k] = f2b(v.w);
  }
  __syncthreads();
#pragma unroll
  for (int p = 0; p < 2; ++p) {
    int idx = p * 256 + tid;
    int n = idx >> 3, kg = (idx & 7) * 8;
    uint4 u = *(uint4*)(&t[n * 72 + kg]);
    *(uint4*)(out + (n0 + n) * K + k0 + kg) = u;
  }
}

// ---------------- GEMM: C[M][N] = A[M][1024] @ Wt^T + bias ----------------
// MODE 0: N=3072, out -> Q/K/V bf16 [64][2048][64], q scaled by 0.125*log2(e)
// MODE 1: N=1024, out -> fp32 d_out
template <int MODE>
__global__ __launch_bounds__(256) void gemm_bf16(const u16* __restrict__ A,
                                                 const u16* __restrict__ B,
                                                 const float* __restrict__ bias,
                                                 float* __restrict__ outf,
                                                 u16* __restrict__ Qo, u16* __restrict__ Ko,
                                                 u16* __restrict__ Vo) {
  __shared__ u16 a_lds[128 * 32];
  __shared__ u16 b_lds[128 * 32];
  int tid = threadIdx.x;
  int l = tid & 63, w = tid >> 6;
  int wr = (w >> 1) * 64, wc = (w & 1) * 64;
  int m0 = blockIdx.y * 128, n0 = blockIdx.x * 128;
  int r15 = l & 15;
  int ka = (l >> 4) * 8;
  int r0 = tid >> 2, kg0 = (tid & 3) * 8;
  f32x4 acc[4][4] = {};
  for (int kt = 0; kt < 32; ++kt) {
    int k0 = kt * 32;
    __syncthreads();
    __builtin_amdgcn_global_load_lds(
        (const __attribute__((address_space(1))) void*)(A + (m0 + r0) * 1024 + k0 + kg0),
        (__attribute__((address_space(3))) void*)(&a_lds[tid * 8]), 16, 0, 0);
    __builtin_amdgcn_global_load_lds(
        (const __attribute__((address_space(1))) void*)(A + (m0 + 64 + r0) * 1024 + k0 + kg0),
        (__attribute__((address_space(3))) void*)(&a_lds[2048 + tid * 8]), 16, 0, 0);
    __builtin_amdgcn_global_load_lds(
        (const __attribute__((address_space(1))) void*)(B + (n0 + r0) * 1024 + k0 + kg0),
        (__attribute__((address_space(3))) void*)(&b_lds[tid * 8]), 16, 0, 0);
    __builtin_amdgcn_global_load_lds(
        (const __attribute__((address_space(1))) void*)(B + (n0 + 64 + r0) * 1024 + k0 + kg0),
        (__attribute__((address_space(3))) void*)(&b_lds[2048 + tid * 8]), 16, 0, 0);
    __syncthreads();
    bf16x8 af[4], bf[4];
#pragma unroll
    for (int i = 0; i < 4; ++i) {
      U4B8 ua; ua.u = *(uint4*)(&a_lds[(wr + i * 16 + r15) * 32 + ka]); af[i] = ua.v;
      U4B8 ub; ub.u = *(uint4*)(&b_lds[(wc + i * 16 + r15) * 32 + ka]); bf[i] = ub.v;
    }
#pragma unroll
    for (int i = 0; i < 4; ++i)
#pragma unroll
      for (int j = 0; j < 4; ++j)
        acc[i][j] = __builtin_amdgcn_mfma_f32_16x16x32_bf16(af[i], bf[j], acc[i][j], 0, 0, 0);
  }
  int rbase = (l >> 4) * 4;
#pragma unroll
  for (int i = 0; i < 4; ++i)
#pragma unroll
    for (int j = 0; j < 4; ++j) {
      int n = n0 + wc + j * 16 + r15;
      float bv = bias[n];
#pragma unroll
      for (int r = 0; r < 4; ++r) {
        int m = m0 + wr + i * 16 + rbase + r;
        float val = acc[i][j][r] + bv;
        if (MODE == 0) {
          int h = n / 192, rem = n % 192;
          int part = rem >> 6, d = rem & 63;
          int b = m >> 11, s = m & 2047;
          int off = (((b * 16 + h) * 2048) + s) * 64 + d;
          // q folded scale: 0.125 * log2(e) so attention can use exp2 directly
          u16 hv = f2b(part == 0 ? val * 0.180336880111f : val);
          if (part == 0) Qo[off] = hv;
          else if (part == 1) Ko[off] = hv;
          else Vo[off] = hv;
        } else {
          outf[m * 1024 + n] = val;
        }
      }
    }
}

// ---------------- flash attention ----------------
// 512 blocks x 512 threads (8 waves, 256 q rows/block, 32 q/wave as 2 q-frags).
// XCD remap: xcd=bid&7, qb=(bid>>3)&7, bh=xcd*8+(bid>>6) -> 8 bh per XCD, K/V
// L2-resident. 8-wave blocks double resident waves/CU vs round 9 (VGPR cap
// 16 waves/CU; 2 blocks x 8 waves; whole grid co-resident, no tail) and halve
// per-wave staging work (1 gll + 1 V b128/thread). Per-instruction lane->bank
// patterns identical to round 9 (0 conflicts measured).
// Swapped QK^T (16x16x32); PV via mfma_f32_16x16x16bf16_1k with reg-resident P
// (QK^T C/D row layout == 16x16x16 A k-layout). exp2 via __builtin_amdgcn_exp2f.
// V^T [d][kv] swz4(d)=((d>>3)^d)&15; K [kv][64] row&7-swizzle via pre-swizzled
// gll source. LDS 32KB dbuf, 1 barrier/tile, T14 split.
__global__ __launch_bounds__(512, 2) void attn_fwd(const u16* __restrict__ Q,
                                                   const u16* __restrict__ K,
                                                   const u16* __restrict__ V,
                                                   u16* __restrict__ O) {
  __shared__ u16 lds[16384];  // [0,8192): K dbuf, [8192,16384): V^T dbuf
  int tid = threadIdx.x;
  int l = tid & 63, w = tid >> 6;
  int g = l >> 4, r15 = l & 15, r7 = r15 & 7;
  int bid = blockIdx.x;
  int qb = (bid >> 3) & 7;
  int bh = (bid & 7) * 8 + (bid >> 6);
  const u16* Kb = K + bh * 131072;
  const u16* Vb = V + bh * 131072;
  int ka = g * 8;
  int qbase = qb * 256 + w * 32;
  U4B8 t0, t1, t2, t3;
  t0.u = *(const uint4*)(Q + bh * 131072 + (qbase + r15) * 64 + ka);
  t1.u = *(const uint4*)(Q + bh * 131072 + (qbase + r15) * 64 + 32 + ka);
  t2.u = *(const uint4*)(Q + bh * 131072 + (qbase + 16 + r15) * 64 + ka);
  t3.u = *(const uint4*)(Q + bh * 131072 + (qbase + 16 + r15) * 64 + 32 + ka);
  bf16x8 qf00 = t0.v, qf01 = t1.v, qf10 = t2.v, qf11 = t3.v;

  // K b128 read addrs: row=c*16+r15, chunk (g)^(row&7); col+32 variant = ^32
  int kaddr[4];
#pragma unroll
  for (int c = 0; c < 4; ++c) kaddr[c] = (c * 16 + r15) * 64 + ((g ^ r7) << 3);
  // V^T b64 read base (c=0): d=16dq+r15; addr(c) = vaddr0 ^ (16c)
  int vaddr0[4];
#pragma unroll
  for (int dq = 0; dq < 4; ++dq) {
    int d = r15 + 16 * dq;
    int vsw = ((d >> 3) ^ d) & 15;
    vaddr0[dq] = 8192 + d * 64 + ((g ^ vsw) << 2);
  }

  // K staging: 512 threads x one gll b128 = full 8KB tile. Source chunk
  // pre-swizzled (m173): row=tid>>3, chunk=(tid&7)^(row&7).
  int krow0 = tid >> 3;
  int kcg = (((tid & 7) ^ (krow0 & 7)) << 3);
  // V staging: thread loads V[sr0][sdg..sdg+7], scatters transposed+swizzled.
  int sr0 = tid >> 3, sdg = (tid & 7) * 8;
  int vwa[8];
#pragma unroll
  for (int i = 0; i < 8; ++i) {
    int d = sdg + i;
    int sw = ((d >> 3) ^ d) & 15;
    vwa[i] = 8192 + d * 64 + ((((sr0 >> 2)) ^ sw) << 2) + (sr0 & 3);
  }
  U4B8 vreg;

#define STAGE(OFFW, TN)                                                                    \
  {                                                                                        \
    int kv0 = (TN) * 64;                                                                   \
    __builtin_amdgcn_global_load_lds(                                                      \
        (const __attribute__((address_space(1))) void*)(Kb + (kv0 + krow0) * 64 + kcg),    \
        (__attribute__((address_space(3))) void*)(&lds[(OFFW) + tid * 8]), 16, 0, 0);      \
    vreg.u = *(const uint4*)(Vb + (kv0 + sr0) * 64 + sdg);                                 \
  }

#define WRITEV(OFFW)                                                                       \
  {                                                                                        \
    _Pragma("unroll") for (int i = 0; i < 8; ++i) {                                        \
      lds[(OFFW) + vwa[i]] = vreg.s[i];                                                    \
    }                                                                                      \
  }

  float l0 = 0.f, l1 = 0.f;
  f32x4 o0[4] = {}, o1[4] = {};

#define COMPUTE(OFFR)                                                                      \
  {                                                                                        \
    _Pragma("unroll") for (int c = 0; c < 4; ++c) {                                        \
      U4B8 k0, k1;                                                                         \
      k0.u = *(const uint4*)(&lds[(OFFR) + kaddr[c]]);                                     \
      k1.u = *(const uint4*)(&lds[(OFFR) + (kaddr[c] ^ 32)]);                              \
      f32x4 z0 = {}, z1 = {};                                                              \
      z0 = __builtin_amdgcn_mfma_f32_16x16x32_bf16(k0.v, qf00, z0, 0, 0, 0);               \
      z0 = __builtin_amdgcn_mfma_f32_16x16x32_bf16(k1.v, qf01, z0, 0, 0, 0);               \
      z1 = __builtin_amdgcn_mfma_f32_16x16x32_bf16(k0.v, qf10, z1, 0, 0, 0);               \
      z1 = __builtin_amdgcn_mfma_f32_16x16x32_bf16(k1.v, qf11, z1, 0, 0, 0);               \
      float a0 = __builtin_amdgcn_exp2f(z0[0]), a1 = __builtin_amdgcn_exp2f(z0[1]);        \
      float a2 = __builtin_amdgcn_exp2f(z0[2]), a3 = __builtin_amdgcn_exp2f(z0[3]);        \
      l0 += (a0 + a1) + (a2 + a3);                                                         \
      U2S4 pa0;                                                                            \
      pa0.h[0] = (__bf16)a0; pa0.h[1] = (__bf16)a1;                                        \
      pa0.h[2] = (__bf16)a2; pa0.h[3] = (__bf16)a3;                                        \
      float b0 = __builtin_amdgcn_exp2f(z1[0]), b1 = __builtin_amdgcn_exp2f(z1[1]);        \
      float b2 = __builtin_amdgcn_exp2f(z1[2]), b3 = __builtin_amdgcn_exp2f(z1[3]);        \
      l1 += (b0 + b1) + (b2 + b3);                                                         \
      U2S4 pa1;                                                                            \
      pa1.h[0] = (__bf16)b0; pa1.h[1] = (__bf16)b1;                                        \
      pa1.h[2] = (__bf16)b2; pa1.h[3] = (__bf16)b3;                                        \
      _Pragma("unroll") for (int dq = 0; dq < 4; ++dq) {                                   \
        U2S4 vb;                                                                           \
        vb.u2 = *(const uint2*)(&lds[(OFFR) + (vaddr0[dq] ^ (16 * c))]);                   \
        o0[dq] = __builtin_amdgcn_mfma_f32_16x16x16bf16_1k(pa0.s, vb.s, o0[dq], 0, 0, 0);  \
        o1[dq] = __builtin_amdgcn_mfma_f32_16x16x16bf16_1k(pa1.s, vb.s, o1[dq], 0, 0, 0);  \
      }                                                                                    \
    }                                                                                      \
  }

  STAGE(0, 0);
  WRITEV(0);
#pragma unroll 1
  for (int tt = 0; tt < 16; ++tt) {
    __syncthreads();
    STAGE(4096, 2 * tt + 1);
    COMPUTE(0);
    WRITEV(4096);
    __syncthreads();
    if (tt < 15) STAGE(0, 2 * tt + 2);
    COMPUTE(4096);
    if (tt < 15) WRITEV(0);
  }
#undef STAGE
#undef WRITEV
#undef COMPUTE

  l0 += __shfl_xor(l0, 16); l0 += __shfl_xor(l0, 32);
  l1 += __shfl_xor(l1, 16); l1 += __shfl_xor(l1, 32);
  float i0 = 1.f / l0, i1 = 1.f / l1;
  float c0[4], c1[4];
#pragma unroll
  for (int j = 0; j < 4; ++j) {
    c0[j] = __shfl(i0, 4 * g + j);
    c1[j] = __shfl(i1, 4 * g + j);
  }
  // ---- staged O epilogue: per-wave 32x64 bf16 tile in reused LDS -> full-line stores ----
  __syncthreads();   // all waves done reading K/V buffers before reuse
  u16* stg = lds + w * 2048;   // 8 waves x 2048 u16 = 16384 (whole lds)
#pragma unroll
  for (int j = 0; j < 4; ++j) {
    int rr0 = 4 * g + j;        // (rr0>>2)&3 == g
    int rr1 = 16 + 4 * g + j;   // (rr1>>2)&3 == g
#pragma unroll
    for (int dq = 0; dq < 4; ++dq) {
      int pc = ((dq ^ g) << 4) + r15;
      stg[rr0 * 64 + pc] = f2b(o0[dq][j] * c0[j]);
      stg[rr1 * 64 + pc] = f2b(o1[dq][j] * c1[j]);
    }
  }
  int b = bh >> 4, h = bh & 15;
  int colpair = (l & 31) * 2;
  int rowsel = l >> 5;
#pragma unroll
  for (int it = 0; it < 16; ++it) {
    int rr = 2 * it + rowsel;
    int phys = rr * 64 + (((colpair >> 4) ^ ((rr >> 2) & 3)) << 4) + (colpair & 15);
    unsigned pv = *(const unsigned*)(&stg[phys]);
    int row = qbase + rr;
    *(unsigned*)(&O[(b * 2048 + row) * 1024 + h * 64 + colpair]) = pv;
  }
}

extern "C" void kernel_launch(void* const* d_in, const int* in_sizes, int n_in,
                              void* d_out, int out_size, void* d_ws, size_t ws_size,
                              hipStream_t stream) {
  const float* x = (const float*)d_in[0];
  const float* Wqkv = (const float*)d_in[1];
  const float* bqkv = (const float*)d_in[2];
  const float* Wout = (const float*)d_in[3];
  const float* bout = (const float*)d_in[4];
  float* out = (float*)d_out;

  u16* ws = (u16*)d_ws;
  u16* WtQ = ws;                    // 3072*1024
  u16* WtO = WtQ + 3072 * 1024;     // 1024*1024
  u16* Xb  = WtO + 1024 * 1024;     // 8192*1024
  u16* Qw  = Xb + 8192 * 1024;      // 64*2048*64
  u16* Kw  = Qw + 64 * 2048 * 64;
  u16* Vw  = Kw + 64 * 2048 * 64;
  u16* Aw  = Vw + 64 * 2048 * 64;   // 8192*1024

  cvt_f32_bf16<<<8192, 256, 0, stream>>>(x, Xb);
  transpose_w<<<dim3(48, 16), 256, 0, stream>>>(Wqkv, WtQ, 1024, 3072);
  transpose_w<<<dim3(16, 16), 256, 0, stream>>>(Wout, WtO, 1024, 1024);
  gemm_bf16<0><<<dim3(24, 64), 256, 0, stream>>>(Xb, WtQ, bqkv, nullptr, Qw, Kw, Vw);
  attn_fwd<<<512, 512, 0, stream>>>(Qw, Kw, Vw, Aw);
  gemm_bf16<1><<<dim3(8, 64), 256, 0, stream>>>(Aw, WtO, bout, out, nullptr, nullptr, nullptr);
}